// Round 1
// baseline (2047.060 us; speedup 1.0000x reference)
//
#include <hip/hip_runtime.h>
#include <math.h>

// Persistent-GRU rollout kernel for MI355X.
// B=32, H=48, T=16, F=256, 3F=768, L=2, S=64, A=16, R=8.
// 8 groups x 32 WGs; group = blockIdx%8 (XCD-local by round-robin heuristic).
// Each WG: 48 gate-rows (16 f x {r,z,n}) of one layer, K=512 ([Wih|Whh]) fp32 in LDS.
// ~112KB LDS/WG -> exactly 1 WG/CU -> all 256 WGs co-resident (spin barriers safe).

#define BLK 256
#define WSTR 516   // padded row stride (floats) for weight LDS (bank-conflict-free)
#define XSTR 260   // padded stride for x/h staging vectors

// LDS layout (float offsets)
#define O_W    0        // 48*516 = 24768
#define O_XB   24768    // 4*260
#define O_HB   25808    // 4*260
#define O_PX   26848    // 192
#define O_PH   27040    // 192
#define O_WSO  27232    // 4*256 (Wso slice)
#define O_SST  28256    // 4*64 (s staging)
#define O_BI   28512    // 48
#define O_BH   28560    // 48
#define O_BSO  28608    // 4
#define LDS_FLOATS 28612
#define LDS_BYTES  (LDS_FLOATS * 4)

// workspace float-region layout (float offsets; region starts at d_ws+4096)
#define O_H0   0         // 2*32*256 double-buffered h layer0
#define O_H1   16384     // 2*32*256
#define O_SEQ  32768     // 32*48*256 tanh(embedded history)
#define O_FAB  425984    // 32*16*256 fa_feat
#define O_PFE  557056    // 32*256 present_feat
#define O_SBF  565248    // 32*64 s feedback

__device__ __forceinline__ float dot4(float4 a, float4 b, float acc) {
  acc = fmaf(a.x, b.x, acc);
  acc = fmaf(a.y, b.y, acc);
  acc = fmaf(a.z, b.z, acc);
  acc = fmaf(a.w, b.w, acc);
  return acc;
}

extern "C" __global__ void __launch_bounds__(BLK, 1)
gru_rollout_kernel(const float* __restrict__ hist_s,
                   const float* __restrict__ hist_a,
                   const float* __restrict__ present_s,
                   const float* __restrict__ future_a,
                   const float* __restrict__ Ws, const float* __restrict__ bs,
                   const float* __restrict__ Wa, const float* __restrict__ ba,
                   const float* __restrict__ Wih, const float* __restrict__ Whh,
                   const float* __restrict__ bih, const float* __restrict__ bhh,
                   const float* __restrict__ Wr, const float* __restrict__ br,
                   const float* __restrict__ Wso, const float* __restrict__ bso,
                   float* __restrict__ out, float* __restrict__ wsf,
                   int* __restrict__ flags)
{
  extern __shared__ float lds[];
  float* Wl  = lds + O_W;
  float* XB  = lds + O_XB;
  float* HB  = lds + O_HB;
  float* PX  = lds + O_PX;
  float* PH  = lds + O_PH;
  float* WSO = lds + O_WSO;
  float* SST = lds + O_SST;
  float* BI  = lds + O_BI;
  float* BH  = lds + O_BH;
  float* BSO = lds + O_BSO;

  const int tid = threadIdx.x;
  const int bid = blockIdx.x;
  const int gid = bid & 7;        // group (== XCD by round-robin heuristic)
  const int mem = bid >> 3;       // member 0..31 within group
  const bool isL0 = (mem < 16);
  const int fc = mem & 15;        // f-chunk: f in [16*fc, 16*fc+16)
  const int layer = isL0 ? 0 : 1;

  float* h0b = wsf + O_H0;
  float* h1b = wsf + O_H1;
  float* seq = wsf + O_SEQ;
  float* fab = wsf + O_FAB;
  float* pfe = wsf + O_PFE;
  float* sbf = wsf + O_SBF;
  int* ctr = flags + gid * 32;    // 128B-padded counter per group
  int bk = 0;

  auto ldsload = [&](float* dst, const float* base, int bstride) {
    int b = tid >> 6, k = (tid & 63) << 2;
    float4 v = *(const float4*)(base + (gid * 4 + b) * bstride + k);
    *(float4*)(dst + b * XSTR + k) = v;
  };
  auto ldszero = [&](float* dst) {
    int b = tid >> 6, k = (tid & 63) << 2;
    *(float4*)(dst + b * XSTR + k) = make_float4(0.f, 0.f, 0.f, 0.f);
  };
  auto barrier = [&]() {
    ++bk;
    __builtin_amdgcn_fence(__ATOMIC_RELEASE, "agent");  // drain our stores to L2
    __syncthreads();
    if (tid == 0) {
      __hip_atomic_fetch_add(ctr, 1, __ATOMIC_RELAXED, __HIP_MEMORY_SCOPE_AGENT);
      int target = 32 * bk, guard = 0;
      while (__hip_atomic_load(ctr, __ATOMIC_RELAXED, __HIP_MEMORY_SCOPE_AGENT) < target) {
        __builtin_amdgcn_s_sleep(1);
        if (++guard > (1 << 21)) break;   // safety: fail loud, don't hang forever
      }
    }
    __syncthreads();
    __builtin_amdgcn_fence(__ATOMIC_ACQUIRE, "agent");  // invalidate L1 for fresh reads
  };

  // GRU cell for this WG's 48 rows x 4 batches. XB = x, HB = h_prev (full vectors).
  // Writes h_new slice (16 f x 4 b) to dst[(gid*4+b)*256 + f].
  auto cell = [&](float* dst) {
    __syncthreads();
    if (tid < 192) {
      int j = tid >> 2, b = tid & 3;
      const float4* wr  = (const float4*)(Wl + j * WSTR);        // Wih part
      const float4* wr2 = (const float4*)(Wl + j * WSTR + 256);  // Whh part
      const float4* xv  = (const float4*)(XB + b * XSTR);
      const float4* hv  = (const float4*)(HB + b * XSTR);
      float ax = 0.f, ah = 0.f;
      #pragma unroll 8
      for (int k = 0; k < 64; ++k) ax = dot4(wr[k], xv[k], ax);
      #pragma unroll 8
      for (int k = 0; k < 64; ++k) ah = dot4(wr2[k], hv[k], ah);
      PX[tid] = ax + BI[j];   // xg + bih
      PH[tid] = ah + BH[j];   // hg + bhh
    }
    __syncthreads();
    if (tid < 64) {
      int i = tid >> 2, b = tid & 3;
      float pr = PX[i * 4 + b] + PH[i * 4 + b];
      float pz = PX[(16 + i) * 4 + b] + PH[(16 + i) * 4 + b];
      float xn = PX[(32 + i) * 4 + b];
      float hn = PH[(32 + i) * 4 + b];
      float r = 1.f / (1.f + expf(-pr));
      float z = 1.f / (1.f + expf(-pz));
      float n = tanhf(xn + r * hn);
      float hp = HB[b * XSTR + fc * 16 + i];
      dst[(gid * 4 + b) * 256 + fc * 16 + i] = (1.f - z) * n + z * hp;
    }
  };

  // ---------------- prologue ----------------
  // weight slice -> LDS (rows j = g*16+i <-> global row g*256 + fc*16 + i)
  for (int idx = tid; idx < 48 * 512; idx += BLK) {
    int j = idx >> 9, k = idx & 511;
    int g = j >> 4, i = j & 15;
    int grow = g * 256 + fc * 16 + i;
    float v = (k < 256) ? Wih[(layer * 768 + grow) * 256 + k]
                        : Whh[(layer * 768 + grow) * 256 + (k - 256)];
    Wl[j * WSTR + k] = v;
  }
  if (tid < 48) {
    int g = tid >> 4, i = tid & 15;
    int grow = g * 256 + fc * 16 + i;
    BI[tid] = bih[layer * 768 + grow];
    BH[tid] = bhh[layer * 768 + grow];
  }
  for (int idx = tid; idx < 4 * 256; idx += BLK) {  // Wso slice rows fc*4..fc*4+3
    int r = idx >> 8, k = idx & 255;
    WSO[idx] = Wso[(fc * 4 + r) * 256 + k];
  }
  if (tid < 4) BSO[tid] = bso[fc * 4 + tid];

  // seq = tanh(embed(history)) for this group's 4 batches; 49152 elems / 32 WGs
  for (int e = mem * 1536 + tid; e < mem * 1536 + 1536; e += BLK) {
    int b = e / 12288, rem = e % 12288, t = rem >> 8, f = rem & 255;
    int gb = gid * 4 + b;
    const float* hs = hist_s + (gb * 48 + t) * 64;
    const float* ha = hist_a + (gb * 48 + t) * 16;
    const float* wsr = Ws + f * 64;
    const float* war = Wa + f * 16;
    float a = bs[f] + ba[f];
    for (int k = 0; k < 64; ++k) a = fmaf(wsr[k], hs[k], a);
    for (int k = 0; k < 16; ++k) a = fmaf(war[k], ha[k], a);
    seq[(gb * 48 + t) * 256 + f] = tanhf(a);
  }
  // fa_feat: 4*16*256 = 16384 elems / 32 WGs
  for (int e = mem * 512 + tid; e < mem * 512 + 512; e += BLK) {
    int b = e >> 12, rem = e & 4095, t = rem >> 8, f = rem & 255;
    int gb = gid * 4 + b;
    const float* fa = future_a + (gb * 16 + t) * 16;
    const float* war = Wa + f * 16;
    float a = ba[f];
    for (int k = 0; k < 16; ++k) a = fmaf(war[k], fa[k], a);
    fab[(gb * 16 + t) * 256 + f] = a;
  }
  // present_feat: 1024 elems / 32 WGs (only tid<32 active)
  for (int e = mem * 32 + tid; e < mem * 32 + 32; e += BLK) {
    int b = e >> 8, f = e & 255;
    int gb = gid * 4 + b;
    const float* ps = present_s + gb * 64;
    const float* wsr = Ws + f * 64;
    float a = bs[f];
    for (int k = 0; k < 64; ++k) a = fmaf(wsr[k], ps[k], a);
    pfe[gb * 256 + f] = a;
  }
  barrier();  // bk=1

  // ---------------- history: 48 steps, L1 pipelined one step behind ----------------
  for (int t = 0; t < 48; ++t) {
    if (isL0) {
      ldsload(XB, seq + t * 256, 12288);                    // x = seq[:,t,:]
      if (t == 0) ldszero(HB);
      else ldsload(HB, h0b + ((t - 1) & 1) * 8192, 256);    // h0_{t-1}
      cell(h0b + (t & 1) * 8192);                           // -> h0_t
    } else {
      if (t > 0) {  // compute h1_{t-1}
        ldsload(XB, h0b + ((t - 1) & 1) * 8192, 256);       // x = h0_{t-1}
        if (t == 1) ldszero(HB);
        else ldsload(HB, h1b + (t & 1) * 8192, 256);        // h1_{t-2}
        cell(h1b + ((t - 1) & 1) * 8192);                   // -> h1_{t-1}
      }
    }
    barrier();  // bk = 2..49
  }
  // tail: h1_47
  if (!isL0) {
    ldsload(XB, h0b + 8192, 256);   // h0_47 (parity 1)
    ldsload(HB, h1b + 0, 256);      // h1_46 (parity 0)
    cell(h1b + 8192);               // -> h1_47 (parity 1)
  }
  barrier();  // bk=50

  // ---------------- rollout: 16 steps x 3 stages ----------------
  for (int t = 0; t < 16; ++t) {
    // stage A: L0 cell (x from pf/s feedback)
    if (isL0) {
      if (t == 0) {
        int b = tid >> 6, k = (tid & 63) << 2;
        float4 p = *(const float4*)(pfe + (gid * 4 + b) * 256 + k);
        float4 f = *(const float4*)(fab + ((gid * 4 + b) * 16 + 0) * 256 + k);
        float4 xv;
        xv.x = tanhf(p.x + f.x); xv.y = tanhf(p.y + f.y);
        xv.z = tanhf(p.z + f.z); xv.w = tanhf(p.w + f.w);
        *(float4*)(XB + b * XSTR + k) = xv;
      } else {
        SST[tid] = sbf[(gid * 4 + (tid >> 6)) * 64 + (tid & 63)];
        __syncthreads();
        // pf = Ws @ s + bs; x = tanh(pf + fa_t). thread = output feature f.
        float acc0 = bs[tid], acc1 = acc0, acc2 = acc0, acc3 = acc0;
        const float4* wsr = (const float4*)(Ws + tid * 64);
        #pragma unroll 4
        for (int j4 = 0; j4 < 16; ++j4) {
          float4 w = wsr[j4];
          acc0 = dot4(w, *(const float4*)(SST + 0 * 64 + j4 * 4), acc0);
          acc1 = dot4(w, *(const float4*)(SST + 1 * 64 + j4 * 4), acc1);
          acc2 = dot4(w, *(const float4*)(SST + 2 * 64 + j4 * 4), acc2);
          acc3 = dot4(w, *(const float4*)(SST + 3 * 64 + j4 * 4), acc3);
        }
        XB[0 * XSTR + tid] = tanhf(acc0 + fab[((gid * 4 + 0) * 16 + t) * 256 + tid]);
        XB[1 * XSTR + tid] = tanhf(acc1 + fab[((gid * 4 + 1) * 16 + t) * 256 + tid]);
        XB[2 * XSTR + tid] = tanhf(acc2 + fab[((gid * 4 + 2) * 16 + t) * 256 + tid]);
        XB[3 * XSTR + tid] = tanhf(acc3 + fab[((gid * 4 + 3) * 16 + t) * 256 + tid]);
      }
      ldsload(HB, h0b + ((t + 1) & 1) * 8192, 256);  // h0_prev
      cell(h0b + (t & 1) * 8192);
    }
    barrier();

    // stage B: L1 cell
    if (!isL0) {
      ldsload(XB, h0b + (t & 1) * 8192, 256);        // x = h0_t
      ldsload(HB, h1b + ((t + 1) & 1) * 8192, 256);  // h1_prev
      cell(h1b + (t & 1) * 8192);
    }
    barrier();

    // stage C: s / r heads (L1 WGs), s feeds back via sbf
    if (!isL0) {
      ldsload(HB, h1b + (t & 1) * 8192, 256);        // full h1_t
      __syncthreads();
      if (tid < 16) {
        int jj = tid >> 2, b = tid & 3;
        const float4* wrow = (const float4*)(WSO + jj * 256);
        const float4* hv = (const float4*)(HB + b * XSTR);
        float a = BSO[jj];
        #pragma unroll 8
        for (int k = 0; k < 64; ++k) a = dot4(wrow[k], hv[k], a);
        float sv = tanhf(a);
        int j = fc * 4 + jj;
        sbf[(gid * 4 + b) * 64 + j] = sv;
        out[4096 + ((gid * 4 + b) * 16 + t) * 64 + j] = sv;   // future_s
      }
      if (mem == 16 && tid >= 32 && tid < 64) {
        int q = (tid - 32) >> 2, b = tid & 3;
        const float4* wrow = (const float4*)(Wr + q * 256);
        const float4* hv = (const float4*)(HB + b * XSTR);
        float a = br[q];
        #pragma unroll 8
        for (int k = 0; k < 64; ++k) a = dot4(wrow[k], hv[k], a);
        out[((gid * 4 + b) * 16 + t) * 8 + q] = tanhf(a);     // future_r
      }
    }
    barrier();
  }
}

extern "C" void kernel_launch(void* const* d_in, const int* in_sizes, int n_in,
                              void* d_out, int out_size, void* d_ws, size_t ws_size,
                              hipStream_t stream) {
  (void)in_sizes; (void)n_in; (void)out_size; (void)ws_size;
  const float* hist_s    = (const float*)d_in[0];
  const float* hist_a    = (const float*)d_in[1];
  const float* present_s = (const float*)d_in[2];
  const float* future_a  = (const float*)d_in[3];
  const float* Ws  = (const float*)d_in[4];
  const float* bs  = (const float*)d_in[5];
  const float* Wa  = (const float*)d_in[6];
  const float* ba  = (const float*)d_in[7];
  const float* Wih = (const float*)d_in[8];
  const float* Whh = (const float*)d_in[9];
  const float* bih = (const float*)d_in[10];
  const float* bhh = (const float*)d_in[11];
  const float* Wr  = (const float*)d_in[12];
  const float* br  = (const float*)d_in[13];
  const float* Wso = (const float*)d_in[14];
  const float* bso = (const float*)d_in[15];
  float* out = (float*)d_out;
  int* flags = (int*)d_ws;
  float* wsf = (float*)((char*)d_ws + 4096);

  // reset barrier counters every launch (graph-capture-legal, no cross-launch state)
  hipMemsetAsync(d_ws, 0, 4096, stream);
  hipFuncSetAttribute(reinterpret_cast<const void*>(gru_rollout_kernel),
                      hipFuncAttributeMaxDynamicSharedMemorySize, LDS_BYTES);
  hipLaunchKernelGGL(gru_rollout_kernel, dim3(256), dim3(BLK), LDS_BYTES, stream,
                     hist_s, hist_a, present_s, future_a,
                     Ws, bs, Wa, ba, Wih, Whh, bih, bhh, Wr, br, Wso, bso,
                     out, wsf, flags);
}

// Round 2
// 642.430 us; speedup vs baseline: 3.1864x; 3.1864x over previous
//
#include <hip/hip_runtime.h>
#include <math.h>

// Persistent-GRU rollout kernel for MI355X.
// B=32, H=48, T=16, F=256, 3F=768, L=2, S=64, A=16, R=8.
// 8 groups x 32 WGs; group = blockIdx%8 (XCD-local by round-robin heuristic,
// but correctness does NOT depend on placement: all cross-WG traffic goes
// through relaxed agent-scope atomics = sc0 sc1 accesses at the LLC, which is
// shared device-wide).
// Each WG: 48 gate-rows (16 f x {r,z,n}) of one layer, K=512 ([Wih|Whh]) fp32 in LDS.
// ~112KB LDS/WG -> exactly 1 WG/CU -> all 256 WGs co-resident (spin barriers safe).

#define BLK 256
#define WSTR 516   // padded row stride (floats) for weight LDS (bank-conflict-free)
#define XSTR 260   // padded stride for x/h staging vectors

// LDS layout (float offsets)
#define O_W    0        // 48*516 = 24768
#define O_XB   24768    // 4*260
#define O_HB   25808    // 4*260
#define O_PX   26848    // 192
#define O_PH   27040    // 192
#define O_WSO  27232    // 4*256 (Wso slice)
#define O_SST  28256    // 4*64 (s staging)
#define O_BI   28512    // 48
#define O_BH   28560    // 48
#define O_BSO  28608    // 4
#define LDS_FLOATS 28612
#define LDS_BYTES  (LDS_FLOATS * 4)

// workspace float-region layout (float offsets; region starts at d_ws+4096)
#define O_H0   0         // 2*32*256 double-buffered h layer0
#define O_H1   16384     // 2*32*256
#define O_SEQ  32768     // 32*48*256 tanh(embedded history)
#define O_FAB  425984    // 32*16*256 fa_feat
#define O_PFE  557056    // 32*256 present_feat
#define O_SBF  565248    // 32*64 s feedback

__device__ __forceinline__ float dot4(float4 a, float4 b, float acc) {
  acc = fmaf(a.x, b.x, acc);
  acc = fmaf(a.y, b.y, acc);
  acc = fmaf(a.z, b.z, acc);
  acc = fmaf(a.w, b.w, acc);
  return acc;
}

// LLC-coherent scalar access (global_load/store dword sc0 sc1): always fresh
// across XCDs, no cache-wide maintenance ops.
__device__ __forceinline__ float aload(const float* p) {
  return __hip_atomic_load(p, __ATOMIC_RELAXED, __HIP_MEMORY_SCOPE_AGENT);
}
__device__ __forceinline__ void astore(float* p, float v) {
  __hip_atomic_store(p, v, __ATOMIC_RELAXED, __HIP_MEMORY_SCOPE_AGENT);
}

extern "C" __global__ void __launch_bounds__(BLK, 1)
gru_rollout_kernel(const float* __restrict__ hist_s,
                   const float* __restrict__ hist_a,
                   const float* __restrict__ present_s,
                   const float* __restrict__ future_a,
                   const float* __restrict__ Ws, const float* __restrict__ bs,
                   const float* __restrict__ Wa, const float* __restrict__ ba,
                   const float* __restrict__ Wih, const float* __restrict__ Whh,
                   const float* __restrict__ bih, const float* __restrict__ bhh,
                   const float* __restrict__ Wr, const float* __restrict__ br,
                   const float* __restrict__ Wso, const float* __restrict__ bso,
                   float* __restrict__ out, float* __restrict__ wsf,
                   int* __restrict__ flags)
{
  extern __shared__ float lds[];
  float* Wl  = lds + O_W;
  float* XB  = lds + O_XB;
  float* HB  = lds + O_HB;
  float* PX  = lds + O_PX;
  float* PH  = lds + O_PH;
  float* WSO = lds + O_WSO;
  float* SST = lds + O_SST;
  float* BI  = lds + O_BI;
  float* BH  = lds + O_BH;
  float* BSO = lds + O_BSO;

  const int tid = threadIdx.x;
  const int bid = blockIdx.x;
  const int gid = bid & 7;        // group (== XCD by round-robin heuristic)
  const int mem = bid >> 3;       // member 0..31 within group
  const bool isL0 = (mem < 16);
  const int fc = mem & 15;        // f-chunk: f in [16*fc, 16*fc+16)
  const int layer = isL0 ? 0 : 1;

  float* h0b = wsf + O_H0;
  float* h1b = wsf + O_H1;
  float* seq = wsf + O_SEQ;
  float* fab = wsf + O_FAB;
  float* pfe = wsf + O_PFE;
  float* sbf = wsf + O_SBF;
  int* ctr = flags + gid * 32;    // 128B-padded counter per group
  int bk = 0;

  // cross-WG vector fetch through LLC (4 scalar sc0sc1 loads per thread)
  auto ldsload = [&](float* dst, const float* base, int bstride) {
    int b = tid >> 6, k = (tid & 63) << 2;
    const float* s = base + (gid * 4 + b) * bstride + k;
    float4 v;
    v.x = aload(s + 0); v.y = aload(s + 1);
    v.z = aload(s + 2); v.w = aload(s + 3);
    *(float4*)(dst + b * XSTR + k) = v;
  };
  auto ldszero = [&](float* dst) {
    int b = tid >> 6, k = (tid & 63) << 2;
    *(float4*)(dst + b * XSTR + k) = make_float4(0.f, 0.f, 0.f, 0.f);
  };

  // Group barrier, fence-free: __syncthreads drains vmcnt(0) (so our sc1
  // stores have reached the LLC), then tid0 bumps the group flag at the LLC
  // and spins until all 32 WGs arrive. Data loads after the barrier are
  // sc0sc1 -> always LLC-fresh. No cache-wide wb/inv anywhere.
  auto barrier = [&]() {
    ++bk;
    asm volatile("s_waitcnt vmcnt(0)" ::: "memory");
    __syncthreads();
    if (tid == 0) {
      __hip_atomic_fetch_add(ctr, 1, __ATOMIC_RELAXED, __HIP_MEMORY_SCOPE_AGENT);
      int target = 32 * bk, guard = 0;
      while (__hip_atomic_load(ctr, __ATOMIC_RELAXED, __HIP_MEMORY_SCOPE_AGENT) < target) {
        __builtin_amdgcn_s_sleep(2);
        if (++guard > (1 << 20)) break;   // failsafe: fail loud, don't hang
      }
    }
    __syncthreads();
  };

  // GRU cell for this WG's 48 rows x 4 batches. XB = x, HB = h_prev (full vectors).
  // Writes h_new slice (16 f x 4 b) to dst[(gid*4+b)*256 + f] via LLC stores.
  auto cell = [&](float* dst) {
    __syncthreads();
    if (tid < 192) {
      int j = tid >> 2, b = tid & 3;
      const float4* wr  = (const float4*)(Wl + j * WSTR);        // Wih part
      const float4* wr2 = (const float4*)(Wl + j * WSTR + 256);  // Whh part
      const float4* xv  = (const float4*)(XB + b * XSTR);
      const float4* hv  = (const float4*)(HB + b * XSTR);
      float ax = 0.f, ah = 0.f;
      #pragma unroll 8
      for (int k = 0; k < 64; ++k) ax = dot4(wr[k], xv[k], ax);
      #pragma unroll 8
      for (int k = 0; k < 64; ++k) ah = dot4(wr2[k], hv[k], ah);
      PX[tid] = ax + BI[j];   // xg + bih
      PH[tid] = ah + BH[j];   // hg + bhh
    }
    __syncthreads();
    if (tid < 64) {
      int i = tid >> 2, b = tid & 3;
      float pr = PX[i * 4 + b] + PH[i * 4 + b];
      float pz = PX[(16 + i) * 4 + b] + PH[(16 + i) * 4 + b];
      float xn = PX[(32 + i) * 4 + b];
      float hn = PH[(32 + i) * 4 + b];
      float r = 1.f / (1.f + expf(-pr));
      float z = 1.f / (1.f + expf(-pz));
      float n = tanhf(xn + r * hn);
      float hp = HB[b * XSTR + fc * 16 + i];
      astore(&dst[(gid * 4 + b) * 256 + fc * 16 + i], (1.f - z) * n + z * hp);
    }
  };

  // ---------------- prologue ----------------
  // weight slice -> LDS (rows j = g*16+i <-> global row g*256 + fc*16 + i)
  for (int idx = tid; idx < 48 * 512; idx += BLK) {
    int j = idx >> 9, k = idx & 511;
    int g = j >> 4, i = j & 15;
    int grow = g * 256 + fc * 16 + i;
    float v = (k < 256) ? Wih[(layer * 768 + grow) * 256 + k]
                        : Whh[(layer * 768 + grow) * 256 + (k - 256)];
    Wl[j * WSTR + k] = v;
  }
  if (tid < 48) {
    int g = tid >> 4, i = tid & 15;
    int grow = g * 256 + fc * 16 + i;
    BI[tid] = bih[layer * 768 + grow];
    BH[tid] = bhh[layer * 768 + grow];
  }
  for (int idx = tid; idx < 4 * 256; idx += BLK) {  // Wso slice rows fc*4..fc*4+3
    int r = idx >> 8, k = idx & 255;
    WSO[idx] = Wso[(fc * 4 + r) * 256 + k];
  }
  if (tid < 4) BSO[tid] = bso[fc * 4 + tid];

  // seq = tanh(embed(history)) for this group's 4 batches; 49152 elems / 32 WGs
  for (int e = mem * 1536 + tid; e < mem * 1536 + 1536; e += BLK) {
    int b = e / 12288, rem = e % 12288, t = rem >> 8, f = rem & 255;
    int gb = gid * 4 + b;
    const float* hs = hist_s + (gb * 48 + t) * 64;
    const float* ha = hist_a + (gb * 48 + t) * 16;
    const float* wsr = Ws + f * 64;
    const float* war = Wa + f * 16;
    float a = bs[f] + ba[f];
    for (int k = 0; k < 64; ++k) a = fmaf(wsr[k], hs[k], a);
    for (int k = 0; k < 16; ++k) a = fmaf(war[k], ha[k], a);
    astore(&seq[(gb * 48 + t) * 256 + f], tanhf(a));
  }
  // fa_feat: 4*16*256 = 16384 elems / 32 WGs
  for (int e = mem * 512 + tid; e < mem * 512 + 512; e += BLK) {
    int b = e >> 12, rem = e & 4095, t = rem >> 8, f = rem & 255;
    int gb = gid * 4 + b;
    const float* fa = future_a + (gb * 16 + t) * 16;
    const float* war = Wa + f * 16;
    float a = ba[f];
    for (int k = 0; k < 16; ++k) a = fmaf(war[k], fa[k], a);
    astore(&fab[(gb * 16 + t) * 256 + f], a);
  }
  // present_feat: 1024 elems / 32 WGs
  for (int e = mem * 32 + tid; e < mem * 32 + 32; e += BLK) {
    int b = e >> 8, f = e & 255;
    int gb = gid * 4 + b;
    const float* ps = present_s + gb * 64;
    const float* wsr = Ws + f * 64;
    float a = bs[f];
    for (int k = 0; k < 64; ++k) a = fmaf(wsr[k], ps[k], a);
    astore(&pfe[gb * 256 + f], a);
  }
  barrier();  // bk=1

  // ---------------- history: 48 steps, L1 pipelined one step behind ----------------
  for (int t = 0; t < 48; ++t) {
    if (isL0) {
      ldsload(XB, seq + t * 256, 12288);                    // x = seq[:,t,:]
      if (t == 0) ldszero(HB);
      else ldsload(HB, h0b + ((t - 1) & 1) * 8192, 256);    // h0_{t-1}
      cell(h0b + (t & 1) * 8192);                           // -> h0_t
    } else {
      if (t > 0) {  // compute h1_{t-1}
        ldsload(XB, h0b + ((t - 1) & 1) * 8192, 256);       // x = h0_{t-1}
        if (t == 1) ldszero(HB);
        else ldsload(HB, h1b + (t & 1) * 8192, 256);        // h1_{t-2}
        cell(h1b + ((t - 1) & 1) * 8192);                   // -> h1_{t-1}
      }
    }
    barrier();  // bk = 2..49
  }
  // tail: h1_47
  if (!isL0) {
    ldsload(XB, h0b + 8192, 256);   // h0_47 (parity 1)
    ldsload(HB, h1b + 0, 256);      // h1_46 (parity 0)
    cell(h1b + 8192);               // -> h1_47 (parity 1)
  }
  barrier();  // bk=50

  // ---------------- rollout: 16 steps x 3 stages ----------------
  for (int t = 0; t < 16; ++t) {
    // stage A: L0 cell (x from pf/s feedback)
    if (isL0) {
      if (t == 0) {
        int b = tid >> 6, k = (tid & 63) << 2;
        const float* p = pfe + (gid * 4 + b) * 256 + k;
        const float* f = fab + ((gid * 4 + b) * 16 + 0) * 256 + k;
        float4 xv;
        xv.x = tanhf(aload(p + 0) + aload(f + 0));
        xv.y = tanhf(aload(p + 1) + aload(f + 1));
        xv.z = tanhf(aload(p + 2) + aload(f + 2));
        xv.w = tanhf(aload(p + 3) + aload(f + 3));
        *(float4*)(XB + b * XSTR + k) = xv;
      } else {
        SST[tid] = aload(&sbf[(gid * 4 + (tid >> 6)) * 64 + (tid & 63)]);
        __syncthreads();
        // pf = Ws @ s + bs; x = tanh(pf + fa_t). thread = output feature f.
        float acc0 = bs[tid], acc1 = acc0, acc2 = acc0, acc3 = acc0;
        const float4* wsr = (const float4*)(Ws + tid * 64);
        #pragma unroll 4
        for (int j4 = 0; j4 < 16; ++j4) {
          float4 w = wsr[j4];
          acc0 = dot4(w, *(const float4*)(SST + 0 * 64 + j4 * 4), acc0);
          acc1 = dot4(w, *(const float4*)(SST + 1 * 64 + j4 * 4), acc1);
          acc2 = dot4(w, *(const float4*)(SST + 2 * 64 + j4 * 4), acc2);
          acc3 = dot4(w, *(const float4*)(SST + 3 * 64 + j4 * 4), acc3);
        }
        XB[0 * XSTR + tid] = tanhf(acc0 + aload(&fab[((gid * 4 + 0) * 16 + t) * 256 + tid]));
        XB[1 * XSTR + tid] = tanhf(acc1 + aload(&fab[((gid * 4 + 1) * 16 + t) * 256 + tid]));
        XB[2 * XSTR + tid] = tanhf(acc2 + aload(&fab[((gid * 4 + 2) * 16 + t) * 256 + tid]));
        XB[3 * XSTR + tid] = tanhf(acc3 + aload(&fab[((gid * 4 + 3) * 16 + t) * 256 + tid]));
      }
      ldsload(HB, h0b + ((t + 1) & 1) * 8192, 256);  // h0_prev
      cell(h0b + (t & 1) * 8192);
    }
    barrier();

    // stage B: L1 cell
    if (!isL0) {
      ldsload(XB, h0b + (t & 1) * 8192, 256);        // x = h0_t
      ldsload(HB, h1b + ((t + 1) & 1) * 8192, 256);  // h1_prev
      cell(h1b + (t & 1) * 8192);
    }
    barrier();

    // stage C: s / r heads (L1 WGs), s feeds back via sbf
    if (!isL0) {
      ldsload(HB, h1b + (t & 1) * 8192, 256);        // full h1_t
      __syncthreads();
      if (tid < 16) {
        int jj = tid >> 2, b = tid & 3;
        const float4* wrow = (const float4*)(WSO + jj * 256);
        const float4* hv = (const float4*)(HB + b * XSTR);
        float a = BSO[jj];
        #pragma unroll 8
        for (int k = 0; k < 64; ++k) a = dot4(wrow[k], hv[k], a);
        float sv = tanhf(a);
        int j = fc * 4 + jj;
        astore(&sbf[(gid * 4 + b) * 64 + j], sv);
        out[4096 + ((gid * 4 + b) * 16 + t) * 64 + j] = sv;   // future_s
      }
      if (mem == 16 && tid >= 32 && tid < 64) {
        int q = (tid - 32) >> 2, b = tid & 3;
        const float4* wrow = (const float4*)(Wr + q * 256);
        const float4* hv = (const float4*)(HB + b * XSTR);
        float a = br[q];
        #pragma unroll 8
        for (int k = 0; k < 64; ++k) a = dot4(wrow[k], hv[k], a);
        out[((gid * 4 + b) * 16 + t) * 8 + q] = tanhf(a);     // future_r
      }
    }
    barrier();
  }
}

extern "C" void kernel_launch(void* const* d_in, const int* in_sizes, int n_in,
                              void* d_out, int out_size, void* d_ws, size_t ws_size,
                              hipStream_t stream) {
  (void)in_sizes; (void)n_in; (void)out_size; (void)ws_size;
  const float* hist_s    = (const float*)d_in[0];
  const float* hist_a    = (const float*)d_in[1];
  const float* present_s = (const float*)d_in[2];
  const float* future_a  = (const float*)d_in[3];
  const float* Ws  = (const float*)d_in[4];
  const float* bs  = (const float*)d_in[5];
  const float* Wa  = (const float*)d_in[6];
  const float* ba  = (const float*)d_in[7];
  const float* Wih = (const float*)d_in[8];
  const float* Whh = (const float*)d_in[9];
  const float* bih = (const float*)d_in[10];
  const float* bhh = (const float*)d_in[11];
  const float* Wr  = (const float*)d_in[12];
  const float* br  = (const float*)d_in[13];
  const float* Wso = (const float*)d_in[14];
  const float* bso = (const float*)d_in[15];
  float* out = (float*)d_out;
  int* flags = (int*)d_ws;
  float* wsf = (float*)((char*)d_ws + 4096);

  // reset barrier counters every launch (graph-capture-legal, no cross-launch state)
  hipMemsetAsync(d_ws, 0, 4096, stream);
  hipFuncSetAttribute(reinterpret_cast<const void*>(gru_rollout_kernel),
                      hipFuncAttributeMaxDynamicSharedMemorySize, LDS_BYTES);
  hipLaunchKernelGGL(gru_rollout_kernel, dim3(256), dim3(BLK), LDS_BYTES, stream,
                     hist_s, hist_a, present_s, future_a,
                     Ws, bs, Wa, ba, Wih, Whh, bih, bhh, Wr, br, Wso, bso,
                     out, wsf, flags);
}

// Round 4
// 466.743 us; speedup vs baseline: 4.3858x; 1.3764x over previous
//
#include <hip/hip_runtime.h>
#include <math.h>

// Persistent-GRU rollout for MI355X. B=32, H=48, T=16, F=256, L=2, S=64, A=16, R=8.
// 8 groups x 32 WGs. Each WG owns 48 gate-rows (16 f x {r,z,n}) of one layer,
// weights REGISTER-RESIDENT: thread (jp,ks) holds rows {3jp..3jp+2} x K-chunk
// [ks*32, ks*32+32) of [Wih|Whh] = 96 VGPRs. Cross-WG h-state via LLC
// (inline-asm sc0 sc1 loads/stores = L1+L2 bypass, coherent device-wide).
// Barrier: per-WG epoch flags at LLC, 32-lane parallel poll. 84KB LDS forces
// 1 WG/CU -> all 256 WGs co-resident (spin-safe).
// R4 fix vs R3: ALL inline-asm outputs are early-clobber ("=&v"). R3 let LLVM
// alias load #1's dest quad with load #2's address pair in llc_load4x2 ->
// clobbered address -> GPU memory fault.

#define BLK 256
#define CH  36          // padded floats per 32-chunk (bank-conflict-free)
#define BST 292         // 8 chunks * 36 + 4

// LDS float offsets
#define O_XQ    0       // 4*292 chunked x
#define O_HQ    1168    // 4*292 chunked h_prev
#define O_PART  2336    // 48*68 partials [j][b*16+ks]
#define O_PRE1  5600    // 48*4
#define O_PRE2  5792    // 16*4
#define O_WSO   5856    // 4*256
#define O_SST   6880    // 4*64 (s / present_s staging)
#define O_BI    7136    // 48
#define O_BH    7184    // 48
#define O_BSO   7232    // 4
#define LDS_BYTES 86016 // 84KB requested -> forces exactly 1 WG/CU

// workspace float-region (starts at d_ws+4096)
#define O_H0   0        // 2*32*256
#define O_H1   16384    // 2*32*256
#define O_SEQ  32768    // 32*48*256
#define O_SBF  81920    // 32*64

using vf4 = __attribute__((ext_vector_type(4))) float;

__device__ __forceinline__ float dotv(vf4 a, vf4 b, float acc) {
  acc = fmaf(a[0], b[0], acc); acc = fmaf(a[1], b[1], acc);
  acc = fmaf(a[2], b[2], acc); acc = fmaf(a[3], b[3], acc);
  return acc;
}

// --- LLC-coherent accesses (bypass L1+L2, served at Infinity Cache) ---
// NOTE: every output is "=&v" (early-clobber). Multi-instruction asm blocks
// would otherwise let the allocator alias one load's dest with another's
// address regs (writeback clobbers the address -> fault).
__device__ __forceinline__ vf4 llc_load4(const float* p) {
  vf4 v;
  asm volatile("global_load_dwordx4 %0, %1, off sc0 sc1\n\ts_waitcnt vmcnt(0)"
               : "=&v"(v) : "v"(p) : "memory");
  return v;
}
__device__ __forceinline__ void llc_load4x2(const float* p1, const float* p2,
                                            vf4& a, vf4& b) {
  asm volatile("global_load_dwordx4 %0, %2, off sc0 sc1\n\t"
               "global_load_dwordx4 %1, %3, off sc0 sc1\n\t"
               "s_waitcnt vmcnt(0)"
               : "=&v"(a), "=&v"(b) : "v"(p1), "v"(p2) : "memory");
}
__device__ __forceinline__ float llc_loadf(const float* p) {
  float v;
  asm volatile("global_load_dword %0, %1, off sc0 sc1\n\ts_waitcnt vmcnt(0)"
               : "=&v"(v) : "v"(p) : "memory");
  return v;
}
__device__ __forceinline__ int llc_loadi(const int* p) {
  int v;
  asm volatile("global_load_dword %0, %1, off sc0 sc1\n\ts_waitcnt vmcnt(0)"
               : "=&v"(v) : "v"(p) : "memory");
  return v;
}
__device__ __forceinline__ void llc_storef(float* p, float v) {
  asm volatile("global_store_dword %0, %1, off sc0 sc1" :: "v"(p), "v"(v) : "memory");
}
__device__ __forceinline__ void llc_storei(int* p, int v) {
  asm volatile("global_store_dword %0, %1, off sc0 sc1" :: "v"(p), "v"(v) : "memory");
}

extern "C" __global__ void __launch_bounds__(BLK, 1)
gru_rollout_kernel(const float* __restrict__ hist_s,
                   const float* __restrict__ hist_a,
                   const float* __restrict__ present_s,
                   const float* __restrict__ future_a,
                   const float* __restrict__ Ws, const float* __restrict__ bs,
                   const float* __restrict__ Wa, const float* __restrict__ ba,
                   const float* __restrict__ Wih, const float* __restrict__ Whh,
                   const float* __restrict__ bih, const float* __restrict__ bhh,
                   const float* __restrict__ Wr, const float* __restrict__ br,
                   const float* __restrict__ Wso, const float* __restrict__ bso,
                   float* __restrict__ out, float* __restrict__ wsf,
                   int* __restrict__ flags)
{
  extern __shared__ float lds[];
  float* XQ   = lds + O_XQ;
  float* HQ   = lds + O_HQ;
  float* PART = lds + O_PART;
  float* PRE1 = lds + O_PRE1;
  float* PRE2 = lds + O_PRE2;
  float* WSO  = lds + O_WSO;
  float* SST  = lds + O_SST;
  float* BI   = lds + O_BI;
  float* BH   = lds + O_BH;
  float* BSO  = lds + O_BSO;

  const int tid = threadIdx.x;
  const int bid = blockIdx.x;
  const int gid = bid & 7;        // group
  const int mem = bid >> 3;       // member 0..31
  const bool isL0 = (mem < 16);
  const int fc = mem & 15;        // f-chunk: features [16fc, 16fc+16)
  const int layer = isL0 ? 0 : 1;

  const int jp = tid >> 4;        // row-triple index 0..15 (rows 3jp..3jp+2)
  const int ks = tid & 15;        // K-chunk 0..15 (k in [32ks, 32ks+32))

  float* h0b = wsf + O_H0;
  float* h1b = wsf + O_H1;
  float* seq = wsf + O_SEQ;
  float* sbf = wsf + O_SBF;
  int* flagbase = flags + gid * 32;
  int bk = 0;

  // ---- epoch-flag barrier: no atomics, 32-lane parallel poll ----
  auto barrier = [&]() {
    ++bk;
    asm volatile("s_waitcnt vmcnt(0)" ::: "memory");
    __syncthreads();
    if (tid == 0) llc_storei(flagbase + mem, bk);
    if (tid < 32) {
      int g = 0;
      while (llc_loadi(flagbase + tid) < bk)
        if (++g > (1 << 20)) break;   // failsafe
    }
    __syncthreads();
  };

  // ---- stage x and/or h vectors (4 batches x 256) from LLC into chunked LDS ----
  // chunk layout: [b][ks'][slot]: off = b*BST + ks'*CH + slot*4 (conflict-free)
  const int sb = tid >> 6, srem = tid & 63;
  const int sko = srem >> 3, ssl = srem & 7;
  const int goff = sko * 32 + ssl * 4;
  const int loff = sb * BST + sko * CH + ssl * 4;
  auto stage_xh = [&](const float* s1, int str1, const float* s2, int str2) {
    vf4 v1 = {0.f, 0.f, 0.f, 0.f}, v2 = {0.f, 0.f, 0.f, 0.f};
    if (s1 && s2) llc_load4x2(s1 + (gid * 4 + sb) * str1 + goff,
                              s2 + (gid * 4 + sb) * str2 + goff, v1, v2);
    else if (s1) v1 = llc_load4(s1 + (gid * 4 + sb) * str1 + goff);
    else if (s2) v2 = llc_load4(s2 + (gid * 4 + sb) * str2 + goff);
    *(vf4*)(XQ + loff) = v1;
    *(vf4*)(HQ + loff) = v2;
  };
  auto stage_h = [&](const float* s2, int str2) {
    vf4 v2 = llc_load4(s2 + (gid * 4 + sb) * str2 + goff);
    *(vf4*)(HQ + loff) = v2;
  };

  // ---- register-resident weights: rows 3jp..3jp+2, chunk ks ----
  vf4 w[3][8];
  {
    const float* src = (ks < 8) ? Wih : Whh;
    const int cb = (ks & 7) * 32;
    #pragma unroll
    for (int r = 0; r < 3; ++r) {
      int j = jp * 3 + r;
      int grow = (layer * 768) + (j >> 4) * 256 + fc * 16 + (j & 15);
      const float* wr = src + grow * 256 + cb;
      #pragma unroll
      for (int c = 0; c < 8; ++c) w[r][c] = *(const vf4*)(wr + c * 4);
    }
  }
  // per-thread LDS base for its K-chunk (XQ for ks<8, HQ for ks>=8)
  const float* xq_base = (ks < 8) ? (XQ + ks * CH) : (HQ + (ks - 8) * CH);

  // ---- GRU cell: FMA on register weights -> LDS reduce -> gates -> LLC store ----
  auto cell = [&](float* dst) {
    __syncthreads();   // staging visible
    float acc[3][4];
    #pragma unroll
    for (int r = 0; r < 3; ++r)
      #pragma unroll
      for (int b = 0; b < 4; ++b) acc[r][b] = 0.f;
    #pragma unroll
    for (int b = 0; b < 4; ++b) {
      const vf4* xb = (const vf4*)(xq_base + b * BST);
      vf4 x0 = xb[0], x1 = xb[1], x2 = xb[2], x3 = xb[3];
      vf4 x4 = xb[4], x5 = xb[5], x6 = xb[6], x7 = xb[7];
      #pragma unroll
      for (int r = 0; r < 3; ++r) {
        float a = acc[r][b];
        a = dotv(w[r][0], x0, a); a = dotv(w[r][1], x1, a);
        a = dotv(w[r][2], x2, a); a = dotv(w[r][3], x3, a);
        a = dotv(w[r][4], x4, a); a = dotv(w[r][5], x5, a);
        a = dotv(w[r][6], x6, a); a = dotv(w[r][7], x7, a);
        acc[r][b] = a;
      }
    }
    #pragma unroll
    for (int r = 0; r < 3; ++r)
      #pragma unroll
      for (int b = 0; b < 4; ++b)
        PART[(jp * 3 + r) * 68 + b * 16 + ks] = acc[r][b];
    __syncthreads();
    if (tid < 192) {   // reduce 16 partials; keep x/h halves separate for n-gate
      int j = tid >> 2, b = tid & 3;
      const vf4* p = (const vf4*)(PART + j * 68 + b * 16);
      vf4 q0 = p[0], q1 = p[1], q2 = p[2], q3 = p[3];
      float s0 = q0[0] + q0[1] + q0[2] + q0[3] + q1[0] + q1[1] + q1[2] + q1[3];
      float s1 = q2[0] + q2[1] + q2[2] + q2[3] + q3[0] + q3[1] + q3[2] + q3[3];
      if (j < 32) PRE1[j * 4 + b] = s0 + s1;
      else { PRE1[j * 4 + b] = s0; PRE2[(j - 32) * 4 + b] = s1; }
    }
    __syncthreads();
    if (tid < 64) {
      int b = tid >> 4, i = tid & 15;
      float pr = PRE1[i * 4 + b] + BI[i] + BH[i];
      float pz = PRE1[(16 + i) * 4 + b] + BI[16 + i] + BH[16 + i];
      float xn = PRE1[(32 + i) * 4 + b] + BI[32 + i];
      float hn = PRE2[i * 4 + b] + BH[32 + i];
      float rg = 1.f / (1.f + expf(-pr));
      float zg = 1.f / (1.f + expf(-pz));
      float ng = tanhf(xn + rg * hn);
      int f = fc * 16 + i;
      float hp = HQ[b * BST + (f >> 5) * CH + (f & 31)];
      llc_storef(&dst[(gid * 4 + b) * 256 + f], (1.f - zg) * ng + zg * hp);
    }
  };

  // ---------------- prologue ----------------
  if (tid < 48) {
    int g = tid >> 4, i = tid & 15;
    int grow = layer * 768 + g * 256 + fc * 16 + i;
    BI[tid] = bih[grow];
    BH[tid] = bhh[grow];
  }
  for (int idx = tid; idx < 4 * 256; idx += BLK) {
    int r = idx >> 8, k = idx & 255;
    WSO[idx] = Wso[(fc * 4 + r) * 256 + k];
  }
  if (tid < 4) BSO[tid] = bso[fc * 4 + tid];

  // seq = tanh(embed(history)) for this group's 4 batches; split over 32 WGs
  for (int e = mem * 1536 + tid; e < mem * 1536 + 1536; e += BLK) {
    int b = e / 12288, rem = e % 12288, t = rem >> 8, f = rem & 255;
    int gb = gid * 4 + b;
    const float* hs = hist_s + (gb * 48 + t) * 64;
    const float* ha = hist_a + (gb * 48 + t) * 16;
    const float* wsr = Ws + f * 64;
    const float* war = Wa + f * 16;
    float a = bs[f] + ba[f];
    for (int k = 0; k < 64; ++k) a = fmaf(wsr[k], hs[k], a);
    for (int k = 0; k < 16; ++k) a = fmaf(war[k], ha[k], a);
    llc_storef(&seq[(gb * 48 + t) * 256 + f], tanhf(a));
  }
  barrier();  // bk=1

  // ---------------- history: 48 steps, L1 one step behind ----------------
  for (int t = 0; t < 48; ++t) {
    if (isL0) {
      stage_xh(seq + t * 256, 12288,
               t == 0 ? (const float*)0 : h0b + ((t - 1) & 1) * 8192, 256);
      cell(h0b + (t & 1) * 8192);
    } else if (t > 0) {
      stage_xh(h0b + ((t - 1) & 1) * 8192, 256,
               t == 1 ? (const float*)0 : h1b + (t & 1) * 8192, 256);
      cell(h1b + ((t - 1) & 1) * 8192);
    }
    barrier();
  }
  if (!isL0) {   // tail: h1_47
    stage_xh(h0b + 8192, 256, h1b + 0, 256);
    cell(h1b + 8192);
  }
  barrier();

  // ---------------- rollout: 16 steps x 3 stages ----------------
  for (int t = 0; t < 16; ++t) {
    // stage A: L0 cell; x = tanh(Ws@v + bs + Wa@fa_t + ba), v = present_s|s_fb
    if (isL0) {
      if (t == 0) SST[tid] = present_s[(gid * 4 + (tid >> 6)) * 64 + (tid & 63)];
      else        SST[tid] = llc_loadf(&sbf[(gid * 4 + (tid >> 6)) * 64 + (tid & 63)]);
      __syncthreads();
      {
        const int f = tid;
        float a0 = bs[f], a1 = a0, a2 = a0, a3 = a0;
        const vf4* wsr = (const vf4*)(Ws + f * 64);
        #pragma unroll 4
        for (int c = 0; c < 16; ++c) {
          vf4 wv = wsr[c];
          a0 = dotv(wv, *(const vf4*)(SST + 0 * 64 + c * 4), a0);
          a1 = dotv(wv, *(const vf4*)(SST + 1 * 64 + c * 4), a1);
          a2 = dotv(wv, *(const vf4*)(SST + 2 * 64 + c * 4), a2);
          a3 = dotv(wv, *(const vf4*)(SST + 3 * 64 + c * 4), a3);
        }
        const vf4* war = (const vf4*)(Wa + f * 16);
        vf4 w0 = war[0], w1 = war[1], w2 = war[2], w3 = war[3];
        float x4[4] = {a0, a1, a2, a3};
        #pragma unroll
        for (int b = 0; b < 4; ++b) {
          const vf4* fa = (const vf4*)(future_a + ((gid * 4 + b) * 16 + t) * 16);
          float a = ba[f] + x4[b];
          a = dotv(w0, fa[0], a); a = dotv(w1, fa[1], a);
          a = dotv(w2, fa[2], a); a = dotv(w3, fa[3], a);
          XQ[b * BST + (f >> 5) * CH + (f & 31)] = tanhf(a);
        }
      }
      stage_h(h0b + ((t + 1) & 1) * 8192, 256);
      cell(h0b + (t & 1) * 8192);
    }
    barrier();

    // stage B: L1 cell
    if (!isL0) {
      stage_xh(h0b + (t & 1) * 8192, 256, h1b + ((t + 1) & 1) * 8192, 256);
      cell(h1b + (t & 1) * 8192);
    }
    barrier();

    // stage C: heads (L1 WGs); s feeds back via sbf
    if (!isL0) {
      stage_h(h1b + (t & 1) * 8192, 256);
      __syncthreads();
      if (tid < 16) {
        int jj = tid >> 2, b = tid & 3;
        const vf4* wrow = (const vf4*)(WSO + jj * 256);
        float a = BSO[jj];
        #pragma unroll
        for (int ko = 0; ko < 8; ++ko) {
          const vf4* hv = (const vf4*)(HQ + b * BST + ko * CH);
          a = dotv(wrow[ko * 8 + 0], hv[0], a); a = dotv(wrow[ko * 8 + 1], hv[1], a);
          a = dotv(wrow[ko * 8 + 2], hv[2], a); a = dotv(wrow[ko * 8 + 3], hv[3], a);
          a = dotv(wrow[ko * 8 + 4], hv[4], a); a = dotv(wrow[ko * 8 + 5], hv[5], a);
          a = dotv(wrow[ko * 8 + 6], hv[6], a); a = dotv(wrow[ko * 8 + 7], hv[7], a);
        }
        float sv = tanhf(a);
        int j = fc * 4 + jj;
        llc_storef(&sbf[(gid * 4 + b) * 64 + j], sv);
        out[4096 + ((gid * 4 + b) * 16 + t) * 64 + j] = sv;   // future_s
      }
      if (mem == 16 && tid >= 32 && tid < 64) {
        int q = (tid - 32) >> 2, b = tid & 3;
        const vf4* wrow = (const vf4*)(Wr + q * 256);
        float a = br[q];
        #pragma unroll
        for (int ko = 0; ko < 8; ++ko) {
          const vf4* hv = (const vf4*)(HQ + b * BST + ko * CH);
          #pragma unroll
          for (int c = 0; c < 8; ++c) a = dotv(wrow[ko * 8 + c], hv[c], a);
        }
        out[((gid * 4 + b) * 16 + t) * 8 + q] = tanhf(a);     // future_r
      }
    }
    barrier();
  }
}

extern "C" void kernel_launch(void* const* d_in, const int* in_sizes, int n_in,
                              void* d_out, int out_size, void* d_ws, size_t ws_size,
                              hipStream_t stream) {
  (void)in_sizes; (void)n_in; (void)out_size; (void)ws_size;
  const float* hist_s    = (const float*)d_in[0];
  const float* hist_a    = (const float*)d_in[1];
  const float* present_s = (const float*)d_in[2];
  const float* future_a  = (const float*)d_in[3];
  const float* Ws  = (const float*)d_in[4];
  const float* bs  = (const float*)d_in[5];
  const float* Wa  = (const float*)d_in[6];
  const float* ba  = (const float*)d_in[7];
  const float* Wih = (const float*)d_in[8];
  const float* Whh = (const float*)d_in[9];
  const float* bih = (const float*)d_in[10];
  const float* bhh = (const float*)d_in[11];
  const float* Wr  = (const float*)d_in[12];
  const float* br  = (const float*)d_in[13];
  const float* Wso = (const float*)d_in[14];
  const float* bso = (const float*)d_in[15];
  float* out = (float*)d_out;
  int* flags = (int*)d_ws;
  float* wsf = (float*)((char*)d_ws + 4096);

  hipMemsetAsync(d_ws, 0, 4096, stream);   // epoch flags -> 0 each launch
  hipFuncSetAttribute(reinterpret_cast<const void*>(gru_rollout_kernel),
                      hipFuncAttributeMaxDynamicSharedMemorySize, LDS_BYTES);
  hipLaunchKernelGGL(gru_rollout_kernel, dim3(256), dim3(BLK), LDS_BYTES, stream,
                     hist_s, hist_a, present_s, future_a,
                     Ws, bs, Wa, ba, Wih, Whh, bih, bhh, Wr, br, Wso, bso,
                     out, wsf, flags);
}

// Round 6
// 390.591 us; speedup vs baseline: 5.2409x; 1.1950x over previous
//
#include <hip/hip_runtime.h>
#include <math.h>

// Persistent-GRU rollout for MI355X. B=32, H=48, T=16, F=256, L=2, S=64, A=16, R=8.
// 8 groups x 32 WGs; group gid = blockIdx%8. Each WG owns 48 gate-rows of one
// layer, weights register-resident (96 VGPR). R6 = R5 structure (heads fused
// into stage A -> 2-barrier rollout; single-sync reduce; paired issue/wait
// staging) with ALL cross-WG data on the proven LLC path (sc0 sc1). The R5
// XCD-local (sc0-only) experiment was unsound across launches (L2 line
// migration) and is removed.

#define BLK 256
#define CH  36          // padded floats per 32-chunk
#define BST 292         // 8*CH + 4

// LDS float offsets
#define O_XQ    0       // 4*292 chunked x
#define O_HQ    1168    // 4*292 chunked h_prev
#define O_H1Q   2336    // 4*292 chunked h1 (heads input)
#define O_PART  3504    // 48*68 partials [j][b*16+ks]
#define O_SST   6768    // 4*64 s / present_s staging
#define O_BI    7024    // 48
#define O_BH    7072    // 48
#define O_BSO   7120    // 64
#define O_BR    7184    // 8
#define O_WSOF  7200    // 64*260 full Wso (L0 WGs)
#define O_WRF   23840   // 8*260 full Wr
#define LDS_FLOATS 25920
#define LDS_BYTES  (LDS_FLOATS * 4)   // 103.7KB -> 1 WG/CU

// workspace float-region (starts at d_ws+4096)
#define O_H0   0        // 2*32*256
#define O_H1   16384    // 2*32*256
#define O_SEQ  32768    // 32*48*256

using vf4 = __attribute__((ext_vector_type(4))) float;

__device__ __forceinline__ float dotv(vf4 a, vf4 b, float acc) {
  acc = fmaf(a[0], b[0], acc); acc = fmaf(a[1], b[1], acc);
  acc = fmaf(a[2], b[2], acc); acc = fmaf(a[3], b[3], acc);
  return acc;
}
__device__ __forceinline__ float hsum(vf4 v) { return (v[0]+v[1]) + (v[2]+v[3]); }

// --- LLC-coherent accesses (sc0 sc1: bypass L1+L2, coherent device-wide) ---
__device__ __forceinline__ int llc_loadi(const int* p) {
  int v;
  asm volatile("global_load_dword %0, %1, off sc0 sc1\n\ts_waitcnt vmcnt(0)"
               : "=&v"(v) : "v"(p) : "memory");
  return v;
}
__device__ __forceinline__ void llc_storei(int* p, int v) {
  asm volatile("global_store_dword %0, %1, off sc0 sc1" :: "v"(p), "v"(v) : "memory");
}
__device__ __forceinline__ void llc_issue4(vf4& v, const float* p) {
  asm volatile("global_load_dwordx4 %0, %1, off sc0 sc1"
               : "=&v"(v) : "v"(p) : "memory");
}
__device__ __forceinline__ void llc_storef(float* p, float v) {
  asm volatile("global_store_dword %0, %1, off sc0 sc1" :: "v"(p), "v"(v) : "memory");
}
__device__ __forceinline__ void vwait() {
  asm volatile("s_waitcnt vmcnt(0)" ::: "memory");
  __builtin_amdgcn_sched_barrier(0);
}

extern "C" __global__ void __launch_bounds__(BLK, 1)
gru_rollout_kernel(const float* __restrict__ hist_s,
                   const float* __restrict__ hist_a,
                   const float* __restrict__ present_s,
                   const float* __restrict__ future_a,
                   const float* __restrict__ Ws, const float* __restrict__ bs,
                   const float* __restrict__ Wa, const float* __restrict__ ba,
                   const float* __restrict__ Wih, const float* __restrict__ Whh,
                   const float* __restrict__ bih, const float* __restrict__ bhh,
                   const float* __restrict__ Wr, const float* __restrict__ br,
                   const float* __restrict__ Wso, const float* __restrict__ bso,
                   float* __restrict__ out, float* __restrict__ wsf,
                   int* __restrict__ flags)
{
  extern __shared__ float lds[];
  float* XQ   = lds + O_XQ;
  float* HQ   = lds + O_HQ;
  float* H1Q  = lds + O_H1Q;
  float* PART = lds + O_PART;
  float* SST  = lds + O_SST;
  float* BI   = lds + O_BI;
  float* BH   = lds + O_BH;
  float* BSO  = lds + O_BSO;
  float* BR   = lds + O_BR;
  float* WSOF = lds + O_WSOF;
  float* WRF  = lds + O_WRF;

  const int tid = threadIdx.x;
  const int bid = blockIdx.x;
  const int gid = bid & 7;
  const int mem = bid >> 3;
  const bool isL0 = (mem < 16);
  const int fc = mem & 15;
  const int layer = isL0 ? 0 : 1;

  const int jp = tid >> 4;        // row-triple 0..15
  const int ks = tid & 15;        // K-chunk 0..15

  float* h0b = wsf + O_H0;
  float* h1b = wsf + O_H1;
  float* seq = wsf + O_SEQ;
  int* flagbase = flags + gid * 32;
  int bk = 0;

  // epoch-flag barrier (flags at LLC, 32-lane parallel poll)
  auto barrier = [&]() {
    ++bk;
    asm volatile("s_waitcnt vmcnt(0)" ::: "memory");
    __syncthreads();
    if (tid == 0) llc_storei(flagbase + mem, bk);
    if (tid < 32) {
      int g = 0;
      while (llc_loadi(flagbase + tid) < bk)
        if (++g > (1 << 20)) break;   // failsafe: fail loud, don't hang
    }
    __syncthreads();
  };

  // staging lane mapping (chunked, conflict-free)
  const int sb = tid >> 6, srem = tid & 63;
  const int sko = srem >> 3, ssl = srem & 7;
  const int goff = sko * 32 + ssl * 4;
  const int loff = sb * BST + sko * CH + ssl * 4;

  // register-resident weights: rows 3jp..3jp+2, chunk ks
  vf4 w[3][8];
  {
    const float* src = (ks < 8) ? Wih : Whh;
    const int cb = (ks & 7) * 32;
    #pragma unroll
    for (int r = 0; r < 3; ++r) {
      int j = jp * 3 + r;
      int grow = (layer * 768) + (j >> 4) * 256 + fc * 16 + (j & 15);
      const float* wr = src + grow * 256 + cb;
      #pragma unroll
      for (int c = 0; c < 8; ++c) w[r][c] = *(const vf4*)(wr + c * 4);
    }
  }
  const float* xq_base = (ks < 8) ? (XQ + ks * CH) : (HQ + (ks - 8) * CH);

  // GRU cell: FMA on reg weights -> PART -> single-sync gate reduce -> store
  auto cell = [&](float* dst) {
    __syncthreads();   // staging/XQ visible
    float a0[4], a1[4], a2[4];
    #pragma unroll
    for (int b = 0; b < 4; ++b) { a0[b] = 0.f; a1[b] = 0.f; a2[b] = 0.f; }
    #pragma unroll
    for (int b = 0; b < 4; ++b) {
      const vf4* xb = (const vf4*)(xq_base + b * BST);
      vf4 x0 = xb[0], x1 = xb[1], x2 = xb[2], x3 = xb[3];
      vf4 x4 = xb[4], x5 = xb[5], x6 = xb[6], x7 = xb[7];
      float a = a0[b];
      a = dotv(w[0][0], x0, a); a = dotv(w[0][1], x1, a);
      a = dotv(w[0][2], x2, a); a = dotv(w[0][3], x3, a);
      a = dotv(w[0][4], x4, a); a = dotv(w[0][5], x5, a);
      a = dotv(w[0][6], x6, a); a = dotv(w[0][7], x7, a);
      a0[b] = a; a = a1[b];
      a = dotv(w[1][0], x0, a); a = dotv(w[1][1], x1, a);
      a = dotv(w[1][2], x2, a); a = dotv(w[1][3], x3, a);
      a = dotv(w[1][4], x4, a); a = dotv(w[1][5], x5, a);
      a = dotv(w[1][6], x6, a); a = dotv(w[1][7], x7, a);
      a1[b] = a; a = a2[b];
      a = dotv(w[2][0], x0, a); a = dotv(w[2][1], x1, a);
      a = dotv(w[2][2], x2, a); a = dotv(w[2][3], x3, a);
      a = dotv(w[2][4], x4, a); a = dotv(w[2][5], x5, a);
      a = dotv(w[2][6], x6, a); a = dotv(w[2][7], x7, a);
      a2[b] = a;
    }
    #pragma unroll
    for (int b = 0; b < 4; ++b) {
      PART[(jp * 3 + 0) * 68 + b * 16 + ks] = a0[b];
      PART[(jp * 3 + 1) * 68 + b * 16 + ks] = a1[b];
      PART[(jp * 3 + 2) * 68 + b * 16 + ks] = a2[b];
    }
    __syncthreads();
    if (tid < 64) {
      int i = tid >> 2, b = tid & 3;
      const vf4* pr4 = (const vf4*)(PART + i * 68 + b * 16);
      const vf4* pz4 = (const vf4*)(PART + (16 + i) * 68 + b * 16);
      const vf4* pn4 = (const vf4*)(PART + (32 + i) * 68 + b * 16);
      float pr = hsum(pr4[0]) + hsum(pr4[1]) + hsum(pr4[2]) + hsum(pr4[3])
               + BI[i] + BH[i];
      float pz = hsum(pz4[0]) + hsum(pz4[1]) + hsum(pz4[2]) + hsum(pz4[3])
               + BI[16 + i] + BH[16 + i];
      float xn = hsum(pn4[0]) + hsum(pn4[1]) + BI[32 + i];
      float hn = hsum(pn4[2]) + hsum(pn4[3]) + BH[32 + i];
      float rg = 1.f / (1.f + expf(-pr));
      float zg = 1.f / (1.f + expf(-pz));
      float ng = tanhf(xn + rg * hn);
      int f = fc * 16 + i;
      float hp = HQ[b * BST + (f >> 5) * CH + (f & 31)];
      llc_storef(dst + (gid * 4 + b) * 256 + f, (1.f - zg) * ng + zg * hp);
    }
  };

  // heads for rollout step tt: s -> SST (all L0 WGs); out r/s by mem==0 only
  auto heads = [&](int tt) {
    int so = tid >> 2, b = tid & 3;
    const vf4* wrow = (const vf4*)(WSOF + so * 260);
    float a = BSO[so];
    #pragma unroll
    for (int ko = 0; ko < 8; ++ko) {
      const vf4* hv = (const vf4*)(H1Q + b * BST + ko * CH);
      a = dotv(wrow[ko * 8 + 0], hv[0], a); a = dotv(wrow[ko * 8 + 1], hv[1], a);
      a = dotv(wrow[ko * 8 + 2], hv[2], a); a = dotv(wrow[ko * 8 + 3], hv[3], a);
      a = dotv(wrow[ko * 8 + 4], hv[4], a); a = dotv(wrow[ko * 8 + 5], hv[5], a);
      a = dotv(wrow[ko * 8 + 6], hv[6], a); a = dotv(wrow[ko * 8 + 7], hv[7], a);
    }
    float sv = tanhf(a);
    SST[b * 64 + so] = sv;
    if (mem == 0) {
      out[4096 + ((gid * 4 + b) * 16 + tt) * 64 + so] = sv;   // future_s
      if (tid < 32) {
        int q = tid >> 2;
        const vf4* wr2 = (const vf4*)(WRF + q * 260);
        float ar = BR[q];
        #pragma unroll
        for (int ko = 0; ko < 8; ++ko) {
          const vf4* hv = (const vf4*)(H1Q + b * BST + ko * CH);
          #pragma unroll
          for (int c = 0; c < 8; ++c) ar = dotv(wr2[ko * 8 + c], hv[c], ar);
        }
        out[((gid * 4 + b) * 16 + tt) * 8 + q] = tanhf(ar);   // future_r
      }
    }
  };

  // x_t = tanh(Ws@SST + bs + Wa@fa_t + ba) -> XQ (all 256 features per WG)
  auto xdot = [&](int t) {
    const int f = tid;
    float a0 = bs[f], a1 = a0, a2 = a0, a3 = a0;
    const vf4* wsr = (const vf4*)(Ws + f * 64);
    #pragma unroll 4
    for (int c = 0; c < 16; ++c) {
      vf4 wv = wsr[c];
      a0 = dotv(wv, *(const vf4*)(SST + 0 * 64 + c * 4), a0);
      a1 = dotv(wv, *(const vf4*)(SST + 1 * 64 + c * 4), a1);
      a2 = dotv(wv, *(const vf4*)(SST + 2 * 64 + c * 4), a2);
      a3 = dotv(wv, *(const vf4*)(SST + 3 * 64 + c * 4), a3);
    }
    const vf4* war = (const vf4*)(Wa + f * 16);
    vf4 w0 = war[0], w1 = war[1], w2 = war[2], w3 = war[3];
    float x4[4] = {a0, a1, a2, a3};
    #pragma unroll
    for (int b = 0; b < 4; ++b) {
      const vf4* fa = (const vf4*)(future_a + ((gid * 4 + b) * 16 + t) * 16);
      float a = ba[f] + x4[b];
      a = dotv(w0, fa[0], a); a = dotv(w1, fa[1], a);
      a = dotv(w2, fa[2], a); a = dotv(w3, fa[3], a);
      XQ[b * BST + (f >> 5) * CH + (f & 31)] = tanhf(a);
    }
  };

  // ---------------- prologue: LDS fills + seq ----------------
  if (tid < 48) {
    int g = tid >> 4, i = tid & 15;
    int grow = layer * 768 + g * 256 + fc * 16 + i;
    BI[tid] = bih[grow];
    BH[tid] = bhh[grow];
  }
  if (isL0) {
    for (int idx = tid; idx < 64 * 256; idx += BLK) {
      int r = idx >> 8, k = idx & 255;
      WSOF[r * 260 + k] = Wso[r * 256 + k];
    }
    for (int idx = tid; idx < 8 * 256; idx += BLK) {
      int r = idx >> 8, k = idx & 255;
      WRF[r * 260 + k] = Wr[r * 256 + k];
    }
    if (tid < 64) BSO[tid] = bso[tid];
    if (tid < 8)  BR[tid] = br[tid];
  }
  // seq = tanh(embed(history)), split over the group's 32 WGs
  for (int e = mem * 1536 + tid; e < mem * 1536 + 1536; e += BLK) {
    int b = e / 12288, rem = e % 12288, t = rem >> 8, f = rem & 255;
    int gb = gid * 4 + b;
    const float* hs = hist_s + (gb * 48 + t) * 64;
    const float* ha = hist_a + (gb * 48 + t) * 16;
    const float* wsr = Ws + f * 64;
    const float* war = Wa + f * 16;
    float a = bs[f] + ba[f];
    for (int k = 0; k < 64; ++k) a = fmaf(wsr[k], hs[k], a);
    for (int k = 0; k < 16; ++k) a = fmaf(war[k], ha[k], a);
    llc_storef(&seq[(gb * 48 + t) * 256 + f], tanhf(a));
  }
  barrier();  // bk=1

  // ---------------- history: 48 steps, L1 one step behind ----------------
  for (int t = 0; t < 48; ++t) {
    if (isL0) {
      vf4 vx, vh;
      llc_issue4(vx, seq + ((gid * 4 + sb) * 48 + t) * 256 + goff);
      if (t > 0) llc_issue4(vh, h0b + ((t - 1) & 1) * 8192 + (gid * 4 + sb) * 256 + goff);
      else       vh = (vf4){0.f, 0.f, 0.f, 0.f};
      vwait();
      *(vf4*)(XQ + loff) = vx;
      *(vf4*)(HQ + loff) = vh;
      cell(h0b + (t & 1) * 8192);
    } else if (t > 0) {
      vf4 vx, vh;
      llc_issue4(vx, h0b + ((t - 1) & 1) * 8192 + (gid * 4 + sb) * 256 + goff);
      if (t > 1) llc_issue4(vh, h1b + (t & 1) * 8192 + (gid * 4 + sb) * 256 + goff);
      else       vh = (vf4){0.f, 0.f, 0.f, 0.f};
      vwait();
      *(vf4*)(XQ + loff) = vx;
      *(vf4*)(HQ + loff) = vh;
      cell(h1b + ((t - 1) & 1) * 8192);
    }
    barrier();  // bk = 2..49
  }
  if (!isL0) {   // tail: h1_47
    vf4 vx, vh;
    llc_issue4(vx, h0b + 8192 + (gid * 4 + sb) * 256 + goff);
    llc_issue4(vh, h1b + 0 + (gid * 4 + sb) * 256 + goff);
    vwait();
    *(vf4*)(XQ + loff) = vx;
    *(vf4*)(HQ + loff) = vh;
    cell(h1b + 8192);
  }
  barrier();  // bk=50

  // ---------------- rollout: 16 steps x 2 stages ----------------
  for (int t = 0; t < 16; ++t) {
    // stage A (L0): [heads(t-1) ->] x_t -> h0_t
    if (isL0) {
      if (t == 0) {
        SST[tid] = present_s[(gid * 4 + (tid >> 6)) * 64 + (tid & 63)];
        vf4 vh;
        llc_issue4(vh, h0b + 8192 + (gid * 4 + sb) * 256 + goff);  // h0_47
        vwait();
        *(vf4*)(HQ + loff) = vh;
        __syncthreads();
      } else {
        vf4 vh, v1;
        llc_issue4(vh, h0b + ((t + 1) & 1) * 8192 + (gid * 4 + sb) * 256 + goff); // h0_{t-1}
        llc_issue4(v1, h1b + ((t + 1) & 1) * 8192 + (gid * 4 + sb) * 256 + goff); // h1_{t-1}
        vwait();
        *(vf4*)(HQ + loff) = vh;
        *(vf4*)(H1Q + loff) = v1;
        __syncthreads();
        heads(t - 1);
        __syncthreads();
      }
      xdot(t);
      cell(h0b + (t & 1) * 8192);
    }
    barrier();

    // stage B (L1): h1_t
    if (!isL0) {
      vf4 vx, vh;
      llc_issue4(vx, h0b + (t & 1) * 8192 + (gid * 4 + sb) * 256 + goff);       // h0_t
      llc_issue4(vh, h1b + ((t + 1) & 1) * 8192 + (gid * 4 + sb) * 256 + goff); // h1_{t-1}
      vwait();
      *(vf4*)(XQ + loff) = vx;
      *(vf4*)(HQ + loff) = vh;
      cell(h1b + (t & 1) * 8192);
    }
    barrier();
  }

  // tail heads for t=15 (only mem==0 WG; h1_15 published by last barrier)
  if (isL0 && mem == 0) {
    vf4 v1;
    llc_issue4(v1, h1b + 8192 + (gid * 4 + sb) * 256 + goff);  // h1_15 (slot 1)
    vwait();
    *(vf4*)(H1Q + loff) = v1;
    __syncthreads();
    heads(15);
  }
}

extern "C" void kernel_launch(void* const* d_in, const int* in_sizes, int n_in,
                              void* d_out, int out_size, void* d_ws, size_t ws_size,
                              hipStream_t stream) {
  (void)in_sizes; (void)n_in; (void)out_size; (void)ws_size;
  const float* hist_s    = (const float*)d_in[0];
  const float* hist_a    = (const float*)d_in[1];
  const float* present_s = (const float*)d_in[2];
  const float* future_a  = (const float*)d_in[3];
  const float* Ws  = (const float*)d_in[4];
  const float* bs  = (const float*)d_in[5];
  const float* Wa  = (const float*)d_in[6];
  const float* ba  = (const float*)d_in[7];
  const float* Wih = (const float*)d_in[8];
  const float* Whh = (const float*)d_in[9];
  const float* bih = (const float*)d_in[10];
  const float* bhh = (const float*)d_in[11];
  const float* Wr  = (const float*)d_in[12];
  const float* br  = (const float*)d_in[13];
  const float* Wso = (const float*)d_in[14];
  const float* bso = (const float*)d_in[15];
  float* out = (float*)d_out;
  int* flags = (int*)d_ws;
  float* wsf = (float*)((char*)d_ws + 4096);

  hipMemsetAsync(d_ws, 0, 4096, stream);   // epoch flags -> 0 each launch
  hipFuncSetAttribute(reinterpret_cast<const void*>(gru_rollout_kernel),
                      hipFuncAttributeMaxDynamicSharedMemorySize, LDS_BYTES);
  hipLaunchKernelGGL(gru_rollout_kernel, dim3(256), dim3(BLK), LDS_BYTES, stream,
                     hist_s, hist_a, present_s, future_a,
                     Ws, bs, Wa, ba, Wih, Whh, bih, bhh, Wr, br, Wso, bso,
                     out, wsf, flags);
}

// Round 8
// 344.798 us; speedup vs baseline: 5.9370x; 1.1328x over previous
//
#include <hip/hip_runtime.h>
#include <math.h>

// Persistent-GRU rollout for MI355X. B=32, H=48, T=16, F=256, L=2, S=64, A=16, R=8.
// 8 groups x 32 WGs; gid = blockIdx%8. Each WG owns 48 gate-rows of one layer,
// weights register-resident. R8: SENTINEL DATA-POLL sync with WRITE-ONCE
// buffers (R7 post-mortem: data-as-flag cannot distinguish epochs on a reused
// ring slot -> stale-valid RAW race at u>=17). h0/h1 get 64 slots each (one
// per unified step) -> every slot transitions poison->value exactly once per
// launch; NO inter-WG barriers at all. Across graph replays values are
// bit-identical (deterministic), so cross-replay early reads are harmless;
// the in-graph memset re-poisons before each replay anyway.

#define BLK 256
#define CH  36          // padded floats per 32-chunk
#define BST 292         // 8*CH + 4

// LDS float offsets
#define O_XQ    0       // 4*292 chunked x
#define O_HQ    1168    // 4*292 chunked h_prev
#define O_H1Q   2336    // 4*292 chunked h1 (heads input)
#define O_PART  3504    // 48*68 partials [j][b*16+ks]
#define O_SST   6768    // 4*64 s / present_s staging
#define O_BI    7024    // 48
#define O_BH    7072    // 48
#define O_BSO   7120    // 64
#define O_BR    7184    // 8
#define O_WSOF  7200    // 64*260 full Wso (L0 WGs)
#define O_WRF   23840   // 8*260 full Wr
#define LDS_FLOATS 25920
#define LDS_BYTES  (LDS_FLOATS * 4)   // 103.7KB -> 1 WG/CU

// workspace float-region (= d_ws); all poisoned 0x7F7F7F7F each launch
#define O_SEQ  0        // 32*48*256 = 393216 (write-once)
#define O_H0R  393216   // 64 slots x 32*256 = 524288 (write-once, slot = u)
#define O_H1R  917504   // 524288
#define WS_FLOATS 1441792
#define POISON_BYTES (WS_FLOATS * 4)   // 5.77 MB

using vf4 = __attribute__((ext_vector_type(4))) float;

__device__ __forceinline__ float dotv(vf4 a, vf4 b, float acc) {
  acc = fmaf(a[0], b[0], acc); acc = fmaf(a[1], b[1], acc);
  acc = fmaf(a[2], b[2], acc); acc = fmaf(a[3], b[3], acc);
  return acc;
}
__device__ __forceinline__ float hsum(vf4 v) { return (v[0]+v[1]) + (v[2]+v[3]); }

// sentinel = 0x7F7F7F7F ~ 3.4e38; every real value here is tanh/blend, |v| <= 1
__device__ __forceinline__ bool valid4(vf4 v) {
  return fabsf(v[0]) < 1.0e30f && fabsf(v[1]) < 1.0e30f &&
         fabsf(v[2]) < 1.0e30f && fabsf(v[3]) < 1.0e30f;
}

// --- LLC-coherent accesses (sc0 sc1: bypass L1+L2, coherent device-wide) ---
__device__ __forceinline__ void llc_issue4(vf4& v, const float* p) {
  asm volatile("global_load_dwordx4 %0, %1, off sc0 sc1"
               : "=&v"(v) : "v"(p) : "memory");
}
__device__ __forceinline__ void llc_storef(float* p, float v) {
  asm volatile("global_store_dword %0, %1, off sc0 sc1" :: "v"(p), "v"(v) : "memory");
}
__device__ __forceinline__ void vwait() {
  asm volatile("s_waitcnt vmcnt(0)" ::: "memory");
  __builtin_amdgcn_sched_barrier(0);
}

extern "C" __global__ void __launch_bounds__(BLK, 1)
gru_rollout_kernel(const float* __restrict__ hist_s,
                   const float* __restrict__ hist_a,
                   const float* __restrict__ present_s,
                   const float* __restrict__ future_a,
                   const float* __restrict__ Ws, const float* __restrict__ bs,
                   const float* __restrict__ Wa, const float* __restrict__ ba,
                   const float* __restrict__ Wih, const float* __restrict__ Whh,
                   const float* __restrict__ bih, const float* __restrict__ bhh,
                   const float* __restrict__ Wr, const float* __restrict__ br,
                   const float* __restrict__ Wso, const float* __restrict__ bso,
                   float* __restrict__ out, float* __restrict__ wsf)
{
  extern __shared__ float lds[];
  float* XQ   = lds + O_XQ;
  float* HQ   = lds + O_HQ;
  float* H1Q  = lds + O_H1Q;
  float* PART = lds + O_PART;
  float* SST  = lds + O_SST;
  float* BI   = lds + O_BI;
  float* BH   = lds + O_BH;
  float* BSO  = lds + O_BSO;
  float* BR   = lds + O_BR;
  float* WSOF = lds + O_WSOF;
  float* WRF  = lds + O_WRF;

  const int tid = threadIdx.x;
  const int bid = blockIdx.x;
  const int gid = bid & 7;
  const int mem = bid >> 3;
  const bool isL0 = (mem < 16);
  const int fc = mem & 15;
  const int layer = isL0 ? 0 : 1;

  const int jp = tid >> 4;        // row-triple 0..15
  const int ks = tid & 15;        // K-chunk 0..15

  float* seq = wsf + O_SEQ;
  float* h0r = wsf + O_H0R;
  float* h1r = wsf + O_H1R;

  // staging lane mapping (chunked, conflict-free)
  const int sb = tid >> 6, srem = tid & 63;
  const int sko = srem >> 3, ssl = srem & 7;
  const int goff = sko * 32 + ssl * 4;
  const int loff = sb * BST + sko * CH + ssl * 4;
  const int gvec = (gid * 4 + sb) * 256 + goff;   // lane offset in a 32x256 slot

  // sentinel polls: loop until all words are real values; the poll IS the load
  auto poll1 = [&](float* d, const float* p) {
    vf4 v; int g = 0;
    for (;;) {
      llc_issue4(v, p); vwait();
      if (valid4(v) || ++g > (1 << 18)) break;
    }
    *(vf4*)d = v;
  };
  auto poll2 = [&](float* d1, const float* p1, float* d2, const float* p2) {
    vf4 v1, v2; int g = 0;
    for (;;) {
      llc_issue4(v1, p1); llc_issue4(v2, p2); vwait();
      if ((valid4(v1) && valid4(v2)) || ++g > (1 << 18)) break;
    }
    *(vf4*)d1 = v1; *(vf4*)d2 = v2;
  };
  auto zeroH = [&](float* d) { *(vf4*)d = (vf4){0.f, 0.f, 0.f, 0.f}; };

  // register-resident weights: rows 3jp..3jp+2, chunk ks
  vf4 w[3][8];
  {
    const float* src = (ks < 8) ? Wih : Whh;
    const int cb = (ks & 7) * 32;
    #pragma unroll
    for (int r = 0; r < 3; ++r) {
      int j = jp * 3 + r;
      int grow = (layer * 768) + (j >> 4) * 256 + fc * 16 + (j & 15);
      const float* wr = src + grow * 256 + cb;
      #pragma unroll
      for (int c = 0; c < 8; ++c) w[r][c] = *(const vf4*)(wr + c * 4);
    }
  }
  const float* xq_base = (ks < 8) ? (XQ + ks * CH) : (HQ + (ks - 8) * CH);

  // GRU cell: FMA on reg weights -> PART -> single-sync gate reduce -> store
  auto cell = [&](float* dst) {
    __syncthreads();   // staging/XQ visible
    float a0[4], a1[4], a2[4];
    #pragma unroll
    for (int b = 0; b < 4; ++b) { a0[b] = 0.f; a1[b] = 0.f; a2[b] = 0.f; }
    #pragma unroll
    for (int b = 0; b < 4; ++b) {
      const vf4* xb = (const vf4*)(xq_base + b * BST);
      vf4 x0 = xb[0], x1 = xb[1], x2 = xb[2], x3 = xb[3];
      vf4 x4 = xb[4], x5 = xb[5], x6 = xb[6], x7 = xb[7];
      float a = a0[b];
      a = dotv(w[0][0], x0, a); a = dotv(w[0][1], x1, a);
      a = dotv(w[0][2], x2, a); a = dotv(w[0][3], x3, a);
      a = dotv(w[0][4], x4, a); a = dotv(w[0][5], x5, a);
      a = dotv(w[0][6], x6, a); a = dotv(w[0][7], x7, a);
      a0[b] = a; a = a1[b];
      a = dotv(w[1][0], x0, a); a = dotv(w[1][1], x1, a);
      a = dotv(w[1][2], x2, a); a = dotv(w[1][3], x3, a);
      a = dotv(w[1][4], x4, a); a = dotv(w[1][5], x5, a);
      a = dotv(w[1][6], x6, a); a = dotv(w[1][7], x7, a);
      a1[b] = a; a = a2[b];
      a = dotv(w[2][0], x0, a); a = dotv(w[2][1], x1, a);
      a = dotv(w[2][2], x2, a); a = dotv(w[2][3], x3, a);
      a = dotv(w[2][4], x4, a); a = dotv(w[2][5], x5, a);
      a = dotv(w[2][6], x6, a); a = dotv(w[2][7], x7, a);
      a2[b] = a;
    }
    #pragma unroll
    for (int b = 0; b < 4; ++b) {
      PART[(jp * 3 + 0) * 68 + b * 16 + ks] = a0[b];
      PART[(jp * 3 + 1) * 68 + b * 16 + ks] = a1[b];
      PART[(jp * 3 + 2) * 68 + b * 16 + ks] = a2[b];
    }
    __syncthreads();
    if (tid < 64) {
      int i = tid >> 2, b = tid & 3;
      const vf4* pr4 = (const vf4*)(PART + i * 68 + b * 16);
      const vf4* pz4 = (const vf4*)(PART + (16 + i) * 68 + b * 16);
      const vf4* pn4 = (const vf4*)(PART + (32 + i) * 68 + b * 16);
      float pr = hsum(pr4[0]) + hsum(pr4[1]) + hsum(pr4[2]) + hsum(pr4[3])
               + BI[i] + BH[i];
      float pz = hsum(pz4[0]) + hsum(pz4[1]) + hsum(pz4[2]) + hsum(pz4[3])
               + BI[16 + i] + BH[16 + i];
      float xn = hsum(pn4[0]) + hsum(pn4[1]) + BI[32 + i];
      float hn = hsum(pn4[2]) + hsum(pn4[3]) + BH[32 + i];
      float rg = 1.f / (1.f + expf(-pr));
      float zg = 1.f / (1.f + expf(-pz));
      float ng = tanhf(xn + rg * hn);
      int f = fc * 16 + i;
      float hp = HQ[b * BST + (f >> 5) * CH + (f & 31)];
      llc_storef(dst + (gid * 4 + b) * 256 + f, (1.f - zg) * ng + zg * hp);
    }
  };

  // heads for rollout step tt: s -> SST (all L0 WGs); out r/s by mem==0 only
  auto heads = [&](int tt) {
    int so = tid >> 2, b = tid & 3;
    const vf4* wrow = (const vf4*)(WSOF + so * 260);
    float a = BSO[so];
    #pragma unroll
    for (int ko = 0; ko < 8; ++ko) {
      const vf4* hv = (const vf4*)(H1Q + b * BST + ko * CH);
      a = dotv(wrow[ko * 8 + 0], hv[0], a); a = dotv(wrow[ko * 8 + 1], hv[1], a);
      a = dotv(wrow[ko * 8 + 2], hv[2], a); a = dotv(wrow[ko * 8 + 3], hv[3], a);
      a = dotv(wrow[ko * 8 + 4], hv[4], a); a = dotv(wrow[ko * 8 + 5], hv[5], a);
      a = dotv(wrow[ko * 8 + 6], hv[6], a); a = dotv(wrow[ko * 8 + 7], hv[7], a);
    }
    float sv = tanhf(a);
    SST[b * 64 + so] = sv;
    if (mem == 0) {
      out[4096 + ((gid * 4 + b) * 16 + tt) * 64 + so] = sv;   // future_s
      if (tid < 32) {
        int q = tid >> 2;
        const vf4* wr2 = (const vf4*)(WRF + q * 260);
        float ar = BR[q];
        #pragma unroll
        for (int ko = 0; ko < 8; ++ko) {
          const vf4* hv = (const vf4*)(H1Q + b * BST + ko * CH);
          #pragma unroll
          for (int c = 0; c < 8; ++c) ar = dotv(wr2[ko * 8 + c], hv[c], ar);
        }
        out[((gid * 4 + b) * 16 + tt) * 8 + q] = tanhf(ar);   // future_r
      }
    }
  };

  // x_t = tanh(Ws@SST + bs + Wa@fa_t + ba) -> XQ (all 256 features per WG)
  auto xdot = [&](int t) {
    const int f = tid;
    float a0 = bs[f], a1 = a0, a2 = a0, a3 = a0;
    const vf4* wsr = (const vf4*)(Ws + f * 64);
    #pragma unroll 4
    for (int c = 0; c < 16; ++c) {
      vf4 wv = wsr[c];
      a0 = dotv(wv, *(const vf4*)(SST + 0 * 64 + c * 4), a0);
      a1 = dotv(wv, *(const vf4*)(SST + 1 * 64 + c * 4), a1);
      a2 = dotv(wv, *(const vf4*)(SST + 2 * 64 + c * 4), a2);
      a3 = dotv(wv, *(const vf4*)(SST + 3 * 64 + c * 4), a3);
    }
    const vf4* war = (const vf4*)(Wa + f * 16);
    vf4 w0 = war[0], w1 = war[1], w2 = war[2], w3 = war[3];
    float x4[4] = {a0, a1, a2, a3};
    #pragma unroll
    for (int b = 0; b < 4; ++b) {
      const vf4* fa = (const vf4*)(future_a + ((gid * 4 + b) * 16 + t) * 16);
      float a = ba[f] + x4[b];
      a = dotv(w0, fa[0], a); a = dotv(w1, fa[1], a);
      a = dotv(w2, fa[2], a); a = dotv(w3, fa[3], a);
      XQ[b * BST + (f >> 5) * CH + (f & 31)] = tanhf(a);
    }
  };

  // ---------------- prologue: LDS fills + seq (write-once) ----------------
  if (tid < 48) {
    int g = tid >> 4, i = tid & 15;
    int grow = layer * 768 + g * 256 + fc * 16 + i;
    BI[tid] = bih[grow];
    BH[tid] = bhh[grow];
  }
  if (isL0) {
    for (int idx = tid; idx < 64 * 256; idx += BLK) {
      int r = idx >> 8, k = idx & 255;
      WSOF[r * 260 + k] = Wso[r * 256 + k];
    }
    for (int idx = tid; idx < 8 * 256; idx += BLK) {
      int r = idx >> 8, k = idx & 255;
      WRF[r * 260 + k] = Wr[r * 256 + k];
    }
    if (tid < 64) BSO[tid] = bso[tid];
    if (tid < 8)  BR[tid] = br[tid];
  }
  // seq = tanh(embed(history)), split over the group's 32 WGs
  for (int e = mem * 1536 + tid; e < mem * 1536 + 1536; e += BLK) {
    int b = e / 12288, rem = e % 12288, t = rem >> 8, f = rem & 255;
    int gb = gid * 4 + b;
    const float* hs = hist_s + (gb * 48 + t) * 64;
    const float* ha = hist_a + (gb * 48 + t) * 16;
    const float* wsr = Ws + f * 64;
    const float* war = Wa + f * 16;
    float a = bs[f] + ba[f];
    for (int k = 0; k < 64; ++k) a = fmaf(wsr[k], hs[k], a);
    for (int k = 0; k < 16; ++k) a = fmaf(war[k], ha[k], a);
    llc_storef(&seq[(gb * 48 + t) * 256 + f], tanhf(a));
  }
  __syncthreads();

  // ------------- unified loop: u = 0..63 (48 history + 16 rollout) -----------
  // write-once slots: h0r/h1r slot u; no inter-WG barriers needed.
  for (int u = 0; u < 64; ++u) {
    if (isL0) {
      if (u < 48) {
        // history L0: x = seq[:,u,:], h_prev = h0[u-1]
        if (u == 0) {
          poll1(XQ + loff, seq + ((gid * 4 + sb) * 48 + u) * 256 + goff);
          zeroH(HQ + loff);
        } else {
          poll2(XQ + loff, seq + ((gid * 4 + sb) * 48 + u) * 256 + goff,
                HQ + loff, h0r + (u - 1) * 8192 + gvec);
        }
        cell(h0r + u * 8192);
      } else {
        const int t = u - 48;
        if (t == 0) {
          SST[tid] = present_s[(gid * 4 + (tid >> 6)) * 64 + (tid & 63)];
          poll1(HQ + loff, h0r + (u - 1) * 8192 + gvec);
          __syncthreads();
        } else {
          poll2(HQ + loff, h0r + (u - 1) * 8192 + gvec,
                H1Q + loff, h1r + (u - 1) * 8192 + gvec);
          __syncthreads();
          heads(t - 1);
          __syncthreads();
        }
        xdot(t);
        cell(h0r + u * 8192);
      }
    } else {
      // L1: x = h0[u], h_prev = h1[u-1]
      if (u == 0) {
        poll1(XQ + loff, h0r + u * 8192 + gvec);
        zeroH(HQ + loff);
      } else {
        poll2(XQ + loff, h0r + u * 8192 + gvec,
              HQ + loff, h1r + (u - 1) * 8192 + gvec);
      }
      cell(h1r + u * 8192);
    }
  }

  // tail heads for t=15 (mem==0 WG polls h1[63])
  if (isL0 && mem == 0) {
    poll1(H1Q + loff, h1r + 63 * 8192 + gvec);
    __syncthreads();
    heads(15);
  }
}

extern "C" void kernel_launch(void* const* d_in, const int* in_sizes, int n_in,
                              void* d_out, int out_size, void* d_ws, size_t ws_size,
                              hipStream_t stream) {
  (void)in_sizes; (void)n_in; (void)out_size; (void)ws_size;
  const float* hist_s    = (const float*)d_in[0];
  const float* hist_a    = (const float*)d_in[1];
  const float* present_s = (const float*)d_in[2];
  const float* future_a  = (const float*)d_in[3];
  const float* Ws  = (const float*)d_in[4];
  const float* bs  = (const float*)d_in[5];
  const float* Wa  = (const float*)d_in[6];
  const float* ba  = (const float*)d_in[7];
  const float* Wih = (const float*)d_in[8];
  const float* Whh = (const float*)d_in[9];
  const float* bih = (const float*)d_in[10];
  const float* bhh = (const float*)d_in[11];
  const float* Wr  = (const float*)d_in[12];
  const float* br  = (const float*)d_in[13];
  const float* Wso = (const float*)d_in[14];
  const float* bso = (const float*)d_in[15];
  float* out = (float*)d_out;
  float* wsf = (float*)d_ws;

  // poison all cross-WG buffers to sentinel each launch (write-once discipline)
  hipMemsetAsync(d_ws, 0x7F, POISON_BYTES, stream);
  hipFuncSetAttribute(reinterpret_cast<const void*>(gru_rollout_kernel),
                      hipFuncAttributeMaxDynamicSharedMemorySize, LDS_BYTES);
  hipLaunchKernelGGL(gru_rollout_kernel, dim3(256), dim3(BLK), LDS_BYTES, stream,
                     hist_s, hist_a, present_s, future_a,
                     Ws, bs, Wa, ba, Wih, Whh, bih, bhh, Wr, br, Wso, bso,
                     out, wsf);
}